// Round 4
// baseline (744.650 us; speedup 1.0000x reference)
//
#include <hip/hip_runtime.h>
#include <hip/hip_bf16.h>

// ---------------------------------------------------------------------------
// TemporallyCalibratedTransformerLayer  (B=64, N=197, C=768, H=12, Dh=64,
// T_TOK=4, F=3072).  All inputs fp32; internal GEMMs in bf16 MFMA.
// R3/R4: 256x256 BK=64 8-phase schedule (T2+T3+T4+T5), counted vmcnt(2),
//     raw s_barrier, setprio around MFMA clusters.  (R4 = R3 resubmit after
//     broker timeout; no code change.)
// ---------------------------------------------------------------------------

typedef __attribute__((ext_vector_type(8))) short  short8;
typedef __attribute__((ext_vector_type(4))) float  float4v;
typedef __attribute__((ext_vector_type(4))) unsigned short ushort4v;
typedef unsigned short ushort;

#define DEV static __device__ __forceinline__

DEV ushort f2bf(float f) {
  union { float f; unsigned u; } v; v.f = f;
  unsigned r = v.u + 0x7fffu + ((v.u >> 16) & 1u);   // RNE
  return (ushort)(r >> 16);
}
DEV float bf2f(ushort h) {
  union { unsigned u; float f; } v; v.u = ((unsigned)h) << 16;
  return v.f;
}

DEV void gld_lds16(const void* g, void* l) {
  __builtin_amdgcn_global_load_lds(
      (const __attribute__((address_space(1))) void*)g,
      (__attribute__((address_space(3))) void*)l, 16, 0, 0);
}

// ---------------------------------------------------------------------------
// fp32 -> bf16 weight conversion
__global__ void wcvt(const float* __restrict__ in, ushort* __restrict__ out, int n4) {
  int i = blockIdx.x * 256 + threadIdx.x;
  if (i >= n4) return;
  float4 f = *((const float4*)in + i);
  ushort4v o;
  o[0] = f2bf(f.x); o[1] = f2bf(f.y); o[2] = f2bf(f.z); o[3] = f2bf(f.w);
  *(ushort4v*)(out + (size_t)i * 4) = o;
}

// ---------------------------------------------------------------------------
// LayerNorm over 768, one WAVE per row (4 rows/block); writes bf16.
__global__ __launch_bounds__(256) void ln_k(const float* __restrict__ x,
                                            const float* __restrict__ w,
                                            const float* __restrict__ b,
                                            ushort* __restrict__ out) {
  int wid = threadIdx.x >> 6, lane = threadIdx.x & 63;
  int row = blockIdx.x * 4 + wid;
  size_t base = (size_t)row * 768;
  const float4* xr = (const float4*)(x + base);
  const float4* w4 = (const float4*)w;
  const float4* b4 = (const float4*)b;
  float4 v[3];
  float s = 0.f, q = 0.f;
#pragma unroll
  for (int j = 0; j < 3; ++j) {
    v[j] = xr[j * 64 + lane];
    s += v[j].x + v[j].y + v[j].z + v[j].w;
    q += v[j].x * v[j].x + v[j].y * v[j].y + v[j].z * v[j].z + v[j].w * v[j].w;
  }
#pragma unroll
  for (int m = 1; m < 64; m <<= 1) { s += __shfl_xor(s, m); q += __shfl_xor(q, m); }
  float mean = s * (1.f / 768.f);
  float var  = q * (1.f / 768.f) - mean * mean;
  float rstd = rsqrtf(var + 1e-6f);
  ushort* orow = out + base;
#pragma unroll
  for (int j = 0; j < 3; ++j) {
    float4 wv = w4[j * 64 + lane], bv = b4[j * 64 + lane];
    ushort4v o;
    o[0] = f2bf((v[j].x - mean) * rstd * wv.x + bv.x);
    o[1] = f2bf((v[j].y - mean) * rstd * wv.y + bv.y);
    o[2] = f2bf((v[j].z - mean) * rstd * wv.z + bv.z);
    o[3] = f2bf((v[j].w - mean) * rstd * wv.w + bv.w);
    *(ushort4v*)(orow + (size_t)(j * 64 + lane) * 4) = o;
  }
}

// ---------------------------------------------------------------------------
// conv1d (k=3, pad=1) over T=4 per-frame CLS tokens, both convq and convk.
__global__ __launch_bounds__(256) void conv_cls(const ushort* __restrict__ h,
                                                const float* __restrict__ wq,
                                                const float* __restrict__ wk,
                                                float* __restrict__ cq,
                                                float* __restrict__ ck) {
  __shared__ float gsh[16][6][48];       // [video][t (0,5 zero-pad)][ci]
  int tid = threadIdx.x;
  int cc = blockIdx.x;                   // cout chunk
  int kc = blockIdx.y;                   // ci chunk
  for (int idx = tid; idx < 16 * 2 * 48; idx += 256) {
    int ci = idx % 48; int t = (idx / 48) & 1; int v = idx / 96;
    gsh[v][t * 5][ci] = 0.f;
  }
  for (int idx = tid; idx < 16 * 4 * 48; idx += 256) {
    int ci = idx % 48; int t = (idx / 48) & 3; int v = idx / 192;
    gsh[v][t + 1][ci] = bf2f(h[(size_t)(v * 4 + t) * 197 * 768 + kc * 48 + ci]);
  }
  __syncthreads();
  int cl = tid >> 2, t = tid & 3;
  int cout = cc * 64 + cl;
  const float* wqp = wq + ((size_t)cout * 768 + kc * 48) * 3;
  const float* wkp = wk + ((size_t)cout * 768 + kc * 48) * 3;
  float aq[16] = {}, ak[16] = {};
  for (int ci = 0; ci < 48; ++ci) {
    float q0 = wqp[ci * 3], q1 = wqp[ci * 3 + 1], q2 = wqp[ci * 3 + 2];
    float k0 = wkp[ci * 3], k1 = wkp[ci * 3 + 1], k2 = wkp[ci * 3 + 2];
#pragma unroll
    for (int v = 0; v < 16; ++v) {
      float g0 = gsh[v][t][ci], g1 = gsh[v][t + 1][ci], g2 = gsh[v][t + 2][ci];
      aq[v] += q0 * g0 + q1 * g1 + q2 * g2;
      ak[v] += k0 * g0 + k1 * g1 + k2 * g2;
    }
  }
#pragma unroll
  for (int v = 0; v < 16; ++v) {
    atomicAdd(&cq[(size_t)(v * 4 + t) * 768 + cout], aq[v]);
    atomicAdd(&ck[(size_t)(v * 4 + t) * 768 + cout], ak[v]);
  }
}

// ---------------------------------------------------------------------------
// 256x256 bf16 MFMA GEMM, BK=64, 512 thr (8 waves 2Mx4N), 8-phase schedule.
// LDS: LA/LB[buf][half][128x64], staged via global_load_lds w/ pre-swizzled
// source (chunk c of row r holds cols (c^(r&7))*8..+8).  Counted vmcnt(2)
// at phases 4+8 only; raw s_barrier; setprio(1) around MFMA clusters.
// C[M,N] = A[M,K] @ W[N,K]^T + bias.   K % 128 == 0, N % 256 == 0.
// EPI: 0 = QKV scatter (+cq/+ck), 1 = proj (+res->f32), 2 = FF1 (GELU->bf16),
// 3 = FF2 (+res -> f32 out).
#define PH_BAR() __builtin_amdgcn_s_barrier()
#define LGKM0() do { asm volatile("s_waitcnt lgkmcnt(0)" ::: "memory"); \
                     __builtin_amdgcn_sched_barrier(0); } while (0)
#define VMC2() do { asm volatile("s_waitcnt vmcnt(2)" ::: "memory"); \
                    __builtin_amdgcn_sched_barrier(0); } while (0)
#define VMC0() do { asm volatile("s_waitcnt vmcnt(0)" ::: "memory"); \
                    __builtin_amdgcn_sched_barrier(0); } while (0)

#define RDA(P, fb) do { _Pragma("unroll") for (int f = 0; f < 4; ++f) { \
    af[0][f] = *(const short8*)((P) + ((fb) + f) * 1024 + swz0); \
    af[1][f] = *(const short8*)((P) + ((fb) + f) * 1024 + swz1); } } while (0)

#define RDB(P, gb, BF) do { _Pragma("unroll") for (int g = 0; g < 2; ++g) { \
    BF[0][g] = *(const short8*)((P) + ((gb) + g) * 1024 + swz0); \
    BF[1][g] = *(const short8*)((P) + ((gb) + g) * 1024 + swz1); } } while (0)

#define MMQ(fb, gb, BF) do { __builtin_amdgcn_s_setprio(1); \
    _Pragma("unroll") for (int f = 0; f < 4; ++f) { \
      _Pragma("unroll") for (int g = 0; g < 2; ++g) { \
        acc[(fb)+f][(gb)+g] = __builtin_amdgcn_mfma_f32_16x16x32_bf16(af[0][f], BF[0][g], acc[(fb)+f][(gb)+g], 0, 0, 0); \
        acc[(fb)+f][(gb)+g] = __builtin_amdgcn_mfma_f32_16x16x32_bf16(af[1][f], BF[1][g], acc[(fb)+f][(gb)+g], 0, 0, 0); \
      } } \
    __builtin_amdgcn_s_setprio(0); } while (0)

#define STGA(tile, h) do { \
    gld_lds16(A + aoff[0][h] + (long)(tile) * 64, &LA[(tile) & 1][h][fl0]); \
    gld_lds16(A + aoff[1][h] + (long)(tile) * 64, &LA[(tile) & 1][h][fl1]); } while (0)
#define STGB(tile, h) do { \
    gld_lds16(W + boff[0][h] + (long)(tile) * 64, &LB[(tile) & 1][h][fl0]); \
    gld_lds16(W + boff[1][h] + (long)(tile) * 64, &LB[(tile) & 1][h][fl1]); } while (0)

template <int EPI>
__global__ __launch_bounds__(512, 2) void gemm8p(
    const ushort* __restrict__ A, const ushort* __restrict__ W,
    int M, int N, int K, int mt, const float* __restrict__ bias,
    float* __restrict__ out_f, ushort* __restrict__ out_h,
    const float* __restrict__ res,
    const float* __restrict__ cq, const float* __restrict__ ck,
    const float* __restrict__ cqb, const float* __restrict__ ckb,
    ushort* __restrict__ Qo, ushort* __restrict__ Ko, ushort* __restrict__ Vo) {
  __shared__ ushort LA[2][2][8192];   // [buf][half][128 rows x 64 cols]  64 KB
  __shared__ ushort LB[2][2][8192];   //                                  64 KB

  // XCD-chunked bijective block swizzle; col-major within chunk (B-panel L2 reuse)
  int nwg = gridDim.x;
  int bid = blockIdx.x;
  int q8 = nwg >> 3, r8 = nwg & 7;
  int xcd = bid & 7, idx = bid >> 3;
  int wg = (xcd < r8 ? xcd * (q8 + 1) : r8 * (q8 + 1) + (xcd - r8) * q8) + idx;
  int tileCol = wg / mt;
  int tileRow = wg - tileCol * mt;

  long rowBase = (long)tileRow * 256;
  int  colBase = tileCol * 256;

  int tid = threadIdx.x;
  int wid = tid >> 6, lane = tid & 63;
  int wr = wid >> 2, wc = wid & 3;         // 2 x 4 wave grid
  int cG = lane >> 4, cl = lane & 15;

  // staging offsets: thread covers 2 x 16B chunks per half-tile (128x64)
  long aoff[2][2], boff[2][2];
#pragma unroll
  for (int j = 0; j < 2; ++j) {
    int flat = j * 512 + tid;
    int r = flat >> 3, c = flat & 7;
    long co = (long)((c ^ (r & 7)) * 8);
#pragma unroll
    for (int h = 0; h < 2; ++h) {
      aoff[j][h] = (long)(rowBase + h * 128 + r) * K + co;
      boff[j][h] = (long)(colBase + h * 128 + r) * K + co;
    }
  }
  int fl0 = tid * 8, fl1 = (512 + tid) * 8;

  // LDS read bases (wave wr reads A-half wr; wave wc reads B-half wc>>1)
  const ushort* pA0 = &LA[0][wr][0] + cl * 64;
  const ushort* pA1 = &LA[1][wr][0] + cl * 64;
  const ushort* pB0 = &LB[0][wc >> 1][0] + ((wc & 1) * 64 + cl) * 64;
  const ushort* pB1 = &LB[1][wc >> 1][0] + ((wc & 1) * 64 + cl) * 64;
  int swz0 = ((cG) ^ (cl & 7)) * 8;
  int swz1 = ((4 + cG) ^ (cl & 7)) * 8;

  short8 af[2][4], bf0[2][2], bf1[2][2];
  float4v acc[8][4] = {};

  // prologue: T0 (4 half-tiles) + T1.Ah0; confirm T0, leave T1.Ah0 in flight
  STGA(0, 0); STGA(0, 1); STGB(0, 0); STGB(0, 1); STGA(1, 0);
  VMC2();
  PH_BAR();

  int NI = K >> 7;                         // 2 K-tiles per iteration
  for (int it = 0; it < NI; ++it) {
    int t1 = 2 * it + 1, t2 = 2 * it + 2, t3 = 2 * it + 3;
    bool more = (it + 1 < NI);
    // ph1: T0 Q1
    RDA(pA0, 0); RDB(pB0, 0, bf0);
    STGB(t1, 0);
    PH_BAR(); LGKM0(); MMQ(0, 0, bf0); PH_BAR();
    // ph2: T0 Q2
    RDB(pB0, 2, bf1);
    STGB(t1, 1);
    PH_BAR(); LGKM0(); MMQ(0, 2, bf1); PH_BAR();
    // ph3: T0 Q3
    RDA(pA0, 4);
    STGA(t1, 1);
    PH_BAR(); LGKM0(); MMQ(4, 2, bf1); PH_BAR();
    // ph4: T0 Q4 (bf0 held); confirm T1 complete
    if (more) { STGA(t2, 0); VMC2(); } else { VMC0(); }
    PH_BAR(); LGKM0(); MMQ(4, 0, bf0); PH_BAR();
    // ph5: T1 Q1
    RDA(pA1, 0); RDB(pB1, 0, bf0);
    if (more) STGA(t2, 1);
    PH_BAR(); LGKM0(); MMQ(0, 0, bf0); PH_BAR();
    // ph6: T1 Q2
    RDB(pB1, 2, bf1);
    if (more) STGB(t2, 0);
    PH_BAR(); LGKM0(); MMQ(0, 2, bf1); PH_BAR();
    // ph7: T1 Q3
    RDA(pA1, 4);
    if (more) STGB(t2, 1);
    PH_BAR(); LGKM0(); MMQ(4, 2, bf1); PH_BAR();
    // ph8: T1 Q4; confirm T2 complete (leaves T3.Ah0 in flight)
    if (more) { STGA(t3, 0); VMC2(); } else { VMC0(); }
    PH_BAR(); LGKM0(); MMQ(4, 0, bf0); PH_BAR();
  }

  // epilogue: D col = lane&15, row = 4*(lane>>4)+j
#pragma unroll
  for (int fi = 0; fi < 8; ++fi) {
    long r0 = rowBase + wr * 128 + fi * 16 + 4 * cG;
#pragma unroll
    for (int fj = 0; fj < 4; ++fj) {
      int col = colBase + wc * 64 + fj * 16 + cl;
      float bc = bias[col];
      float4v a = acc[fi][fj];
#pragma unroll
      for (int j = 0; j < 4; ++j) {
        long row = r0 + j;
        if (row >= M) continue;
        float v = a[j] + bc;
        if constexpr (EPI == 0) {
          int sec = col / 768; int ccc = col - sec * 768;
          int bi = (int)(row / 197); int ni = (int)(row - (long)bi * 197);
          size_t oidx = ((size_t)(bi * 12 + (ccc >> 6)) * 197 + ni) * 64 + (ccc & 63);
          if (sec == 0)      { v += cq[bi * 768 + ccc] + cqb[ccc]; Qo[oidx] = f2bf(v); }
          else if (sec == 1) { v += ck[bi * 768 + ccc] + ckb[ccc]; Ko[oidx] = f2bf(v); }
          else               { Vo[oidx] = f2bf(v); }
        } else if constexpr (EPI == 1 || EPI == 3) {
          size_t idx = (size_t)row * N + col;
          out_f[idx] = v + res[idx];
        } else {
          size_t idx = (size_t)row * N + col;
          float g = 0.5f * v * (1.0f + erff(v * 0.70710678118f));
          out_h[idx] = f2bf(g);
        }
      }
    }
  }
}

// ---------------------------------------------------------------------------
// Attention: one block (4 waves) per (b,h).  N=197 padded to 224 in LDS.
__global__ __launch_bounds__(256, 2) void attn_k(const ushort* __restrict__ Q,
                                                 const ushort* __restrict__ Kg,
                                                 const ushort* __restrict__ Vg,
                                                 ushort* __restrict__ O) {
  __shared__ ushort Ks[224 * 64];   // [n][d], chunk ^= n&7
  __shared__ ushort Vt[64 * 224];   // [d][n], n-block ^= (d&7)<<3
  __shared__ ushort Ps[4][16 * 40]; // per-wave P chunk [16][32+pad8]
  int g = blockIdx.x;
  int bi = g / 12, hh = g - bi * 12;
  size_t gbase = (size_t)g * 197 * 64;
  int tid = threadIdx.x, wid = tid >> 6, lane = tid & 63;
  int cG = lane >> 4, cl = lane & 15;

  {
    int rr = tid >> 3, ch = tid & 7;
#pragma unroll
    for (int i = 0; i < 7; ++i) {
      int n = rr + 32 * i;
      short8 kv = {0, 0, 0, 0, 0, 0, 0, 0};
      if (n < 197) kv = *(const short8*)(Kg + gbase + (size_t)n * 64 + ch * 8);
      *(short8*)(Ks + n * 64 + (ch ^ (n & 7)) * 8) = kv;
      short8 vv = {0, 0, 0, 0, 0, 0, 0, 0};
      if (n < 197) vv = *(const short8*)(Vg + gbase + (size_t)n * 64 + ch * 8);
#pragma unroll
      for (int j = 0; j < 8; ++j) {
        int dd = ch * 8 + j;
        Vt[dd * 224 + (n ^ ((dd & 7) << 3))] = ((ushort*)&vv)[j];
      }
    }
  }
  __syncthreads();

  for (int rt = wid; rt < 13; rt += 4) {
    int nq = rt * 16 + cl; if (nq > 196) nq = 196;
    short8 aq0 = *(const short8*)(Q + gbase + (size_t)nq * 64 + 8 * cG);
    short8 aq1 = *(const short8*)(Q + gbase + (size_t)nq * 64 + 32 + 8 * cG);
    float4v s[14];
#pragma unroll
    for (int ct = 0; ct < 14; ++ct) {
      float4v a = {0.f, 0.f, 0.f, 0.f};
      int np = ct * 16 + cl;
      short8 b0 = *(const short8*)(Ks + np * 64 + ((cG    ) ^ (np & 7)) * 8);
      short8 b1 = *(const short8*)(Ks + np * 64 + ((4 + cG) ^ (np & 7)) * 8);
      a = __builtin_amdgcn_mfma_f32_16x16x32_bf16(aq0, b0, a, 0, 0, 0);
      a = __builtin_amdgcn_mfma_f32_16x16x32_bf16(aq1, b1, a, 0, 0, 0);
      s[ct] = a;
    }
    float mx[4] = {-1e30f, -1e30f, -1e30f, -1e30f};
#pragma unroll
    for (int ct = 0; ct < 14; ++ct) {
      int colv = ct * 16 + cl;
#pragma unroll
      for (int j = 0; j < 4; ++j) {
        float v = (colv < 197) ? s[ct][j] * 0.125f : -1e30f;
        s[ct][j] = v;
        mx[j] = fmaxf(mx[j], v);
      }
    }
#pragma unroll
    for (int m = 1; m < 16; m <<= 1)
#pragma unroll
      for (int j = 0; j < 4; ++j) mx[j] = fmaxf(mx[j], __shfl_xor(mx[j], m));
    float sum[4] = {0.f, 0.f, 0.f, 0.f};
#pragma unroll
    for (int ct = 0; ct < 14; ++ct)
#pragma unroll
      for (int j = 0; j < 4; ++j) {
        float p = __expf(s[ct][j] - mx[j]);
        s[ct][j] = p;
        sum[j] += p;
      }
#pragma unroll
    for (int m = 1; m < 16; m <<= 1)
#pragma unroll
      for (int j = 0; j < 4; ++j) sum[j] += __shfl_xor(sum[j], m);
    float rs[4];
#pragma unroll
    for (int j = 0; j < 4; ++j) rs[j] = 1.0f / sum[j];

    float4v oa[4] = {};
    ushort* P = &Ps[wid][0];
#pragma unroll
    for (int ks = 0; ks < 7; ++ks) {
#pragma unroll
      for (int t = 0; t < 2; ++t) {
        int ct = 2 * ks + t;
#pragma unroll
        for (int j = 0; j < 4; ++j)
          P[(4 * cG + j) * 40 + t * 16 + cl] = f2bf(s[ct][j]);
      }
      short8 pa = *(const short8*)(P + cl * 40 + 8 * cG);
#pragma unroll
      for (int dt = 0; dt < 4; ++dt) {
        int dd = dt * 16 + cl;
        short8 bv = *(const short8*)(Vt + dd * 224 + ((ks * 32 + 8 * cG) ^ ((dd & 7) << 3)));
        oa[dt] = __builtin_amdgcn_mfma_f32_16x16x32_bf16(pa, bv, oa[dt], 0, 0, 0);
      }
    }
#pragma unroll
    for (int dt = 0; dt < 4; ++dt)
#pragma unroll
      for (int j = 0; j < 4; ++j) {
        int n2 = rt * 16 + 4 * cG + j;
        if (n2 < 197)
          O[(size_t)(bi * 197 + n2) * 768 + hh * 64 + dt * 16 + cl] = f2bf(oa[dt][j] * rs[j]);
      }
  }
}

// ---------------------------------------------------------------------------
extern "C" void kernel_launch(void* const* d_in, const int* in_sizes, int n_in,
                              void* d_out, int out_size, void* d_ws, size_t ws_size,
                              hipStream_t stream) {
  const float* x     = (const float*)d_in[0];
  const float* ln1w  = (const float*)d_in[1];
  const float* ln1b  = (const float*)d_in[2];
  const float* qkvw  = (const float*)d_in[3];
  const float* qkvb  = (const float*)d_in[4];
  const float* cqw   = (const float*)d_in[5];
  const float* cqb   = (const float*)d_in[6];
  const float* ckw   = (const float*)d_in[7];
  const float* ckb   = (const float*)d_in[8];
  const float* projw = (const float*)d_in[9];
  const float* projb = (const float*)d_in[10];
  const float* ln2w  = (const float*)d_in[11];
  const float* ln2b  = (const float*)d_in[12];
  const float* ff1w  = (const float*)d_in[13];
  const float* ff1b  = (const float*)d_in[14];
  const float* ff2w  = (const float*)d_in[15];
  const float* ff2b  = (const float*)d_in[16];
  float* out = (float*)d_out;

  char* ws = (char*)d_ws;
  const size_t SZ = (size_t)12608 * 768 * 2;          // 19,365,888 B
  ushort* Qb  = (ushort*)(ws);
  ushort* Kb  = (ushort*)(ws + SZ);
  ushort* Vb  = (ushort*)(ws + 2 * SZ);
  ushort* Ob  = (ushort*)(ws + 3 * SZ);
  ushort* ffh = (ushort*)(ws);        // overlays Q..O after proj
  ushort* hb  = (ushort*)(ws + 4 * SZ);
  float* x1 = (float*)(ws + 5 * SZ);
  float* cq = (float*)(ws + 5 * SZ + (size_t)12608 * 768 * 4);
  float* ck = cq + 49152;
  ushort* Wqkv  = (ushort*)(ck + 49152);
  ushort* Wproj = Wqkv + 1769472;
  ushort* Wff1  = Wproj + 589824;
  ushort* Wff2  = Wff1 + 2359296;

  // weights -> bf16 (inputs restored every timed call, so convert every call)
  wcvt<<<1728, 256, 0, stream>>>(qkvw, Wqkv, 442368);
  wcvt<<<576,  256, 0, stream>>>(projw, Wproj, 147456);
  wcvt<<<2304, 256, 0, stream>>>(ff1w, Wff1, 589824);
  wcvt<<<2304, 256, 0, stream>>>(ff2w, Wff2, 589824);

  // LN1
  ln_k<<<3152, 256, 0, stream>>>(x, ln1w, ln1b, hb);

  // temporal conv on CLS tokens
  hipMemsetAsync(cq, 0, 2 * 49152 * sizeof(float), stream);
  conv_cls<<<dim3(12, 16), 256, 0, stream>>>(hb, cqw, ckw, cq, ck);

  // QKV projection (+cq/+ck fold, scatter to (b*12+h, n, d)); mt=50, 9 col-tiles
  gemm8p<0><<<450, 512, 0, stream>>>(hb, Wqkv, 12608, 2304, 768, 50, qkvb,
      nullptr, nullptr, nullptr, cq, ck, cqb, ckb, Qb, Kb, Vb);

  // attention
  attn_k<<<768, 256, 0, stream>>>(Qb, Kb, Vb, Ob);

  // output projection + residual -> x1 (f32); 3 col-tiles
  gemm8p<1><<<150, 512, 0, stream>>>(Ob, Wproj, 12608, 768, 768, 50, projb,
      x1, nullptr, x, nullptr, nullptr, nullptr, nullptr, nullptr, nullptr, nullptr);

  // LN2
  ln_k<<<3152, 256, 0, stream>>>(x1, ln2w, ln2b, hb);

  // FF1 + GELU -> bf16; 12 col-tiles
  gemm8p<2><<<600, 512, 0, stream>>>(hb, Wff1, 12608, 3072, 768, 50, ff1b,
      nullptr, ffh, nullptr, nullptr, nullptr, nullptr, nullptr, nullptr, nullptr, nullptr);

  // FF2 + residual -> out (f32); 3 col-tiles
  gemm8p<3><<<150, 512, 0, stream>>>(ffh, Wff2, 12608, 768, 3072, 50, ff2b,
      out, nullptr, x1, nullptr, nullptr, nullptr, nullptr, nullptr, nullptr, nullptr);
}

// Round 5
// 579.377 us; speedup vs baseline: 1.2853x; 1.2853x over previous
//
#include <hip/hip_runtime.h>
#include <hip/hip_bf16.h>

// ---------------------------------------------------------------------------
// TemporallyCalibratedTransformerLayer  (B=64, N=197, C=768, H=12, Dh=64,
// T_TOK=4, F=3072).  All inputs fp32; internal GEMMs in bf16 MFMA.
// R5: revert to R1-proven 128x128 structure (3-4 blocks/CU TLP regime);
//     + BK=64 (half the barriers), + tanh-GELU (no erff), + XCD swizzle.
// ---------------------------------------------------------------------------

typedef __attribute__((ext_vector_type(8))) short  short8;
typedef __attribute__((ext_vector_type(4))) float  float4v;
typedef __attribute__((ext_vector_type(4))) unsigned short ushort4v;
typedef unsigned short ushort;

#define DEV static __device__ __forceinline__

DEV ushort f2bf(float f) {
  union { float f; unsigned u; } v; v.f = f;
  unsigned r = v.u + 0x7fffu + ((v.u >> 16) & 1u);   // RNE
  return (ushort)(r >> 16);
}
DEV float bf2f(ushort h) {
  union { unsigned u; float f; } v; v.u = ((unsigned)h) << 16;
  return v.f;
}

DEV void gld_lds16(const void* g, void* l) {
  __builtin_amdgcn_global_load_lds(
      (const __attribute__((address_space(1))) void*)g,
      (__attribute__((address_space(3))) void*)l, 16, 0, 0);
}

// tanh-form GELU (max abs err < 1e-3 vs exact erf form; threshold is 0.114)
DEV float gelu_f(float v) {
  float u = v * (0.7978845608f + 0.0356774081f * v * v);
  float e = __expf(2.0f * u);
  float t = 1.0f - __fdividef(2.0f, e + 1.0f);   // tanh(u)
  return 0.5f * v * (1.0f + t);
}

// ---------------------------------------------------------------------------
// fp32 -> bf16 weight conversion
__global__ void wcvt(const float* __restrict__ in, ushort* __restrict__ out, int n4) {
  int i = blockIdx.x * 256 + threadIdx.x;
  if (i >= n4) return;
  float4 f = *((const float4*)in + i);
  ushort4v o;
  o[0] = f2bf(f.x); o[1] = f2bf(f.y); o[2] = f2bf(f.z); o[3] = f2bf(f.w);
  *(ushort4v*)(out + (size_t)i * 4) = o;
}

// ---------------------------------------------------------------------------
// LayerNorm over 768, one WAVE per row (4 rows/block); writes bf16.
__global__ __launch_bounds__(256) void ln_k(const float* __restrict__ x,
                                            const float* __restrict__ w,
                                            const float* __restrict__ b,
                                            ushort* __restrict__ out) {
  int wid = threadIdx.x >> 6, lane = threadIdx.x & 63;
  int row = blockIdx.x * 4 + wid;
  size_t base = (size_t)row * 768;
  const float4* xr = (const float4*)(x + base);
  const float4* w4 = (const float4*)w;
  const float4* b4 = (const float4*)b;
  float4 v[3];
  float s = 0.f, q = 0.f;
#pragma unroll
  for (int j = 0; j < 3; ++j) {
    v[j] = xr[j * 64 + lane];
    s += v[j].x + v[j].y + v[j].z + v[j].w;
    q += v[j].x * v[j].x + v[j].y * v[j].y + v[j].z * v[j].z + v[j].w * v[j].w;
  }
#pragma unroll
  for (int m = 1; m < 64; m <<= 1) { s += __shfl_xor(s, m); q += __shfl_xor(q, m); }
  float mean = s * (1.f / 768.f);
  float var  = q * (1.f / 768.f) - mean * mean;
  float rstd = rsqrtf(var + 1e-6f);
  ushort* orow = out + base;
#pragma unroll
  for (int j = 0; j < 3; ++j) {
    float4 wv = w4[j * 64 + lane], bv = b4[j * 64 + lane];
    ushort4v o;
    o[0] = f2bf((v[j].x - mean) * rstd * wv.x + bv.x);
    o[1] = f2bf((v[j].y - mean) * rstd * wv.y + bv.y);
    o[2] = f2bf((v[j].z - mean) * rstd * wv.z + bv.z);
    o[3] = f2bf((v[j].w - mean) * rstd * wv.w + bv.w);
    *(ushort4v*)(orow + (size_t)(j * 64 + lane) * 4) = o;
  }
}

// ---------------------------------------------------------------------------
// conv1d (k=3, pad=1) over T=4 per-frame CLS tokens, both convq and convk.
__global__ __launch_bounds__(256) void conv_cls(const ushort* __restrict__ h,
                                                const float* __restrict__ wq,
                                                const float* __restrict__ wk,
                                                float* __restrict__ cq,
                                                float* __restrict__ ck) {
  __shared__ float gsh[16][6][48];       // [video][t (0,5 zero-pad)][ci]
  int tid = threadIdx.x;
  int cc = blockIdx.x;                   // cout chunk
  int kc = blockIdx.y;                   // ci chunk
  for (int idx = tid; idx < 16 * 2 * 48; idx += 256) {
    int ci = idx % 48; int t = (idx / 48) & 1; int v = idx / 96;
    gsh[v][t * 5][ci] = 0.f;
  }
  for (int idx = tid; idx < 16 * 4 * 48; idx += 256) {
    int ci = idx % 48; int t = (idx / 48) & 3; int v = idx / 192;
    gsh[v][t + 1][ci] = bf2f(h[(size_t)(v * 4 + t) * 197 * 768 + kc * 48 + ci]);
  }
  __syncthreads();
  int cl = tid >> 2, t = tid & 3;
  int cout = cc * 64 + cl;
  const float* wqp = wq + ((size_t)cout * 768 + kc * 48) * 3;
  const float* wkp = wk + ((size_t)cout * 768 + kc * 48) * 3;
  float aq[16] = {}, ak[16] = {};
  for (int ci = 0; ci < 48; ++ci) {
    float q0 = wqp[ci * 3], q1 = wqp[ci * 3 + 1], q2 = wqp[ci * 3 + 2];
    float k0 = wkp[ci * 3], k1 = wkp[ci * 3 + 1], k2 = wkp[ci * 3 + 2];
#pragma unroll
    for (int v = 0; v < 16; ++v) {
      float g0 = gsh[v][t][ci], g1 = gsh[v][t + 1][ci], g2 = gsh[v][t + 2][ci];
      aq[v] += q0 * g0 + q1 * g1 + q2 * g2;
      ak[v] += k0 * g0 + k1 * g1 + k2 * g2;
    }
  }
#pragma unroll
  for (int v = 0; v < 16; ++v) {
    atomicAdd(&cq[(size_t)(v * 4 + t) * 768 + cout], aq[v]);
    atomicAdd(&ck[(size_t)(v * 4 + t) * 768 + cout], ak[v]);
  }
}

// ---------------------------------------------------------------------------
// bf16 MFMA GEMM: C[M,N] = A[M,K] @ W[N,K]^T + bias.
// 128x128 tile, BK=64, 4 waves (2x2) of 64x64, single-buffered 32 KiB LDS,
// global_load_lds(16B) staging with XOR-swizzle (8 chunks/row), 2 barriers
// per 64-K-step.  ~3-4 blocks/CU -> cross-block TLP hides staging latency.
// EPI: 0 = QKV scatter (+cq/+ck), 1 = proj (+res->f32), 2 = FF1 (GELU->bf16),
// 3 = FF2 (+res->f32 out).
template <int EPI>
__global__ __launch_bounds__(256, 2) void gemm_k(
    const ushort* __restrict__ A, const ushort* __restrict__ W,
    int M, int N, int K, int mt, const float* __restrict__ bias,
    float* __restrict__ out_f, ushort* __restrict__ out_h,
    const float* __restrict__ res,
    const float* __restrict__ cq, const float* __restrict__ ck,
    const float* __restrict__ cqb, const float* __restrict__ ckb,
    ushort* __restrict__ Qo, ushort* __restrict__ Ko, ushort* __restrict__ Vo) {
  __shared__ ushort As[128 * 64];   // 16 KB
  __shared__ ushort Bs[128 * 64];   // 16 KB

  // bijective XCD-chunked swizzle; row-fastest within chunk (W-panel reuse)
  int nwg = gridDim.x;
  int bid = blockIdx.x;
  int q8 = nwg >> 3, r8 = nwg & 7;
  int xcd = bid & 7, sub = bid >> 3;
  int wg = (xcd < r8 ? xcd * (q8 + 1) : r8 * (q8 + 1) + (xcd - r8) * q8) + sub;
  int tileCol = wg / mt;
  int tileRow = wg - tileCol * mt;

  long rowBase = (long)tileRow * 128;
  int  colBase = tileCol * 128;

  int tid = threadIdx.x;
  int wid = tid >> 6, lane = tid & 63;
  int wr = wid >> 1, wc = wid & 1;          // 2x2 wave grid, 64x64 each
  int cG = lane >> 4, cl = lane & 15;

  // staging: 4 x 16B per matrix per K-tile per thread (16 KB per matrix)
  const ushort* asrc[4];
  const ushort* wsrc[4];
  int dsto[4];
#pragma unroll
  for (int j = 0; j < 4; ++j) {
    int flat = j * 256 + tid;               // 0..1023
    int r = flat >> 3, c = flat & 7;        // row 0..127, 16B chunk 0..7
    long ar = rowBase + r; if (ar > M - 1) ar = M - 1;
    long co = (long)((c ^ (r & 7)) * 8);    // inverse-swizzled source col
    asrc[j] = A + ar * (size_t)K + co;
    wsrc[j] = W + (size_t)(colBase + r) * K + co;
    dsto[j] = flat * 8;                     // shorts
  }

  float4v acc[4][4] = {};

  for (int kt = 0; kt < K; kt += 64) {
    __syncthreads();                        // WAR: previous tile's reads done
#pragma unroll
    for (int j = 0; j < 4; ++j) {
      gld_lds16(asrc[j] + kt, As + dsto[j]);
      gld_lds16(wsrc[j] + kt, Bs + dsto[j]);
    }
    __syncthreads();                        // RAW: loads landed (vmcnt drain)
#pragma unroll
    for (int ks = 0; ks < 2; ++ks) {
      short8 af[4], bfr[4];
#pragma unroll
      for (int fi = 0; fi < 4; ++fi) {
        int r = wr * 64 + fi * 16 + cl;
        af[fi] = *(const short8*)(As + r * 64 + ((((ks << 2) | cG) ^ (r & 7)) * 8));
      }
#pragma unroll
      for (int fj = 0; fj < 4; ++fj) {
        int r = wc * 64 + fj * 16 + cl;
        bfr[fj] = *(const short8*)(Bs + r * 64 + ((((ks << 2) | cG) ^ (r & 7)) * 8));
      }
#pragma unroll
      for (int fi = 0; fi < 4; ++fi)
#pragma unroll
        for (int fj = 0; fj < 4; ++fj)
          acc[fi][fj] = __builtin_amdgcn_mfma_f32_16x16x32_bf16(af[fi], bfr[fj], acc[fi][fj], 0, 0, 0);
    }
  }

  // epilogue: D col = lane&15, row = 4*(lane>>4)+j
#pragma unroll
  for (int fi = 0; fi < 4; ++fi) {
    long r0 = rowBase + wr * 64 + fi * 16 + 4 * cG;
#pragma unroll
    for (int fj = 0; fj < 4; ++fj) {
      int col = colBase + wc * 64 + fj * 16 + cl;
      float bc = bias[col];
      float4v a = acc[fi][fj];
#pragma unroll
      for (int j = 0; j < 4; ++j) {
        long row = r0 + j;
        if (row >= M) continue;
        float v = a[j] + bc;
        if constexpr (EPI == 0) {
          int sec = col / 768; int ccc = col - sec * 768;
          int bi = (int)(row / 197); int ni = (int)(row - (long)bi * 197);
          size_t oidx = ((size_t)(bi * 12 + (ccc >> 6)) * 197 + ni) * 64 + (ccc & 63);
          if (sec == 0)      { v += cq[bi * 768 + ccc] + cqb[ccc]; Qo[oidx] = f2bf(v); }
          else if (sec == 1) { v += ck[bi * 768 + ccc] + ckb[ccc]; Ko[oidx] = f2bf(v); }
          else               { Vo[oidx] = f2bf(v); }
        } else if constexpr (EPI == 1 || EPI == 3) {
          size_t idx = (size_t)row * N + col;
          out_f[idx] = v + res[idx];
        } else {
          size_t idx = (size_t)row * N + col;
          out_h[idx] = f2bf(gelu_f(v));
        }
      }
    }
  }
}

// ---------------------------------------------------------------------------
// Attention: one block (4 waves) per (b,h).  N=197 padded to 224 in LDS.
__global__ __launch_bounds__(256, 2) void attn_k(const ushort* __restrict__ Q,
                                                 const ushort* __restrict__ Kg,
                                                 const ushort* __restrict__ Vg,
                                                 ushort* __restrict__ O) {
  __shared__ ushort Ks[224 * 64];   // [n][d], chunk ^= n&7
  __shared__ ushort Vt[64 * 224];   // [d][n], n-block ^= (d&7)<<3
  __shared__ ushort Ps[4][16 * 40]; // per-wave P chunk [16][32+pad8]
  int g = blockIdx.x;
  int bi = g / 12, hh = g - bi * 12;
  size_t gbase = (size_t)g * 197 * 64;
  int tid = threadIdx.x, wid = tid >> 6, lane = tid & 63;
  int cG = lane >> 4, cl = lane & 15;

  {
    int rr = tid >> 3, ch = tid & 7;
#pragma unroll
    for (int i = 0; i < 7; ++i) {
      int n = rr + 32 * i;
      short8 kv = {0, 0, 0, 0, 0, 0, 0, 0};
      if (n < 197) kv = *(const short8*)(Kg + gbase + (size_t)n * 64 + ch * 8);
      *(short8*)(Ks + n * 64 + (ch ^ (n & 7)) * 8) = kv;
      short8 vv = {0, 0, 0, 0, 0, 0, 0, 0};
      if (n < 197) vv = *(const short8*)(Vg + gbase + (size_t)n * 64 + ch * 8);
#pragma unroll
      for (int j = 0; j < 8; ++j) {
        int dd = ch * 8 + j;
        Vt[dd * 224 + (n ^ ((dd & 7) << 3))] = ((ushort*)&vv)[j];
      }
    }
  }
  __syncthreads();

  for (int rt = wid; rt < 13; rt += 4) {
    int nq = rt * 16 + cl; if (nq > 196) nq = 196;
    short8 aq0 = *(const short8*)(Q + gbase + (size_t)nq * 64 + 8 * cG);
    short8 aq1 = *(const short8*)(Q + gbase + (size_t)nq * 64 + 32 + 8 * cG);
    float4v s[14];
#pragma unroll
    for (int ct = 0; ct < 14; ++ct) {
      float4v a = {0.f, 0.f, 0.f, 0.f};
      int np = ct * 16 + cl;
      short8 b0 = *(const short8*)(Ks + np * 64 + ((cG    ) ^ (np & 7)) * 8);
      short8 b1 = *(const short8*)(Ks + np * 64 + ((4 + cG) ^ (np & 7)) * 8);
      a = __builtin_amdgcn_mfma_f32_16x16x32_bf16(aq0, b0, a, 0, 0, 0);
      a = __builtin_amdgcn_mfma_f32_16x16x32_bf16(aq1, b1, a, 0, 0, 0);
      s[ct] = a;
    }
    float mx[4] = {-1e30f, -1e30f, -1e30f, -1e30f};
#pragma unroll
    for (int ct = 0; ct < 14; ++ct) {
      int colv = ct * 16 + cl;
#pragma unroll
      for (int j = 0; j < 4; ++j) {
        float v = (colv < 197) ? s[ct][j] * 0.125f : -1e30f;
        s[ct][j] = v;
        mx[j] = fmaxf(mx[j], v);
      }
    }
#pragma unroll
    for (int m = 1; m < 16; m <<= 1)
#pragma unroll
      for (int j = 0; j < 4; ++j) mx[j] = fmaxf(mx[j], __shfl_xor(mx[j], m));
    float sum[4] = {0.f, 0.f, 0.f, 0.f};
#pragma unroll
    for (int ct = 0; ct < 14; ++ct)
#pragma unroll
      for (int j = 0; j < 4; ++j) {
        float p = __expf(s[ct][j] - mx[j]);
        s[ct][j] = p;
        sum[j] += p;
      }
#pragma unroll
    for (int m = 1; m < 16; m <<= 1)
#pragma unroll
      for (int j = 0; j < 4; ++j) sum[j] += __shfl_xor(sum[j], m);
    float rs[4];
#pragma unroll
    for (int j = 0; j < 4; ++j) rs[j] = 1.0f / sum[j];

    float4v oa[4] = {};
    ushort* P = &Ps[wid][0];
#pragma unroll
    for (int ks = 0; ks < 7; ++ks) {
#pragma unroll
      for (int t = 0; t < 2; ++t) {
        int ct = 2 * ks + t;
#pragma unroll
        for (int j = 0; j < 4; ++j)
          P[(4 * cG + j) * 40 + t * 16 + cl] = f2bf(s[ct][j]);
      }
      short8 pa = *(const short8*)(P + cl * 40 + 8 * cG);
#pragma unroll
      for (int dt = 0; dt < 4; ++dt) {
        int dd = dt * 16 + cl;
        short8 bv = *(const short8*)(Vt + dd * 224 + ((ks * 32 + 8 * cG) ^ ((dd & 7) << 3)));
        oa[dt] = __builtin_amdgcn_mfma_f32_16x16x32_bf16(pa, bv, oa[dt], 0, 0, 0);
      }
    }
#pragma unroll
    for (int dt = 0; dt < 4; ++dt)
#pragma unroll
      for (int j = 0; j < 4; ++j) {
        int n2 = rt * 16 + 4 * cG + j;
        if (n2 < 197)
          O[(size_t)(bi * 197 + n2) * 768 + hh * 64 + dt * 16 + cl] = f2bf(oa[dt][j] * rs[j]);
      }
  }
}

// ---------------------------------------------------------------------------
extern "C" void kernel_launch(void* const* d_in, const int* in_sizes, int n_in,
                              void* d_out, int out_size, void* d_ws, size_t ws_size,
                              hipStream_t stream) {
  const float* x     = (const float*)d_in[0];
  const float* ln1w  = (const float*)d_in[1];
  const float* ln1b  = (const float*)d_in[2];
  const float* qkvw  = (const float*)d_in[3];
  const float* qkvb  = (const float*)d_in[4];
  const float* cqw   = (const float*)d_in[5];
  const float* cqb   = (const float*)d_in[6];
  const float* ckw   = (const float*)d_in[7];
  const float* ckb   = (const float*)d_in[8];
  const float* projw = (const float*)d_in[9];
  const float* projb = (const float*)d_in[10];
  const float* ln2w  = (const float*)d_in[11];
  const float* ln2b  = (const float*)d_in[12];
  const float* ff1w  = (const float*)d_in[13];
  const float* ff1b  = (const float*)d_in[14];
  const float* ff2w  = (const float*)d_in[15];
  const float* ff2b  = (const float*)d_in[16];
  float* out = (float*)d_out;

  char* ws = (char*)d_ws;
  const size_t SZ = (size_t)12608 * 768 * 2;          // 19,365,888 B
  ushort* Qb  = (ushort*)(ws);
  ushort* Kb  = (ushort*)(ws + SZ);
  ushort* Vb  = (ushort*)(ws + 2 * SZ);
  ushort* Ob  = (ushort*)(ws + 3 * SZ);
  ushort* ffh = (ushort*)(ws);        // overlays Q..O after proj
  ushort* hb  = (ushort*)(ws + 4 * SZ);
  float* x1 = (float*)(ws + 5 * SZ);
  float* cq = (float*)(ws + 5 * SZ + (size_t)12608 * 768 * 4);
  float* ck = cq + 49152;
  ushort* Wqkv  = (ushort*)(ck + 49152);
  ushort* Wproj = Wqkv + 1769472;
  ushort* Wff1  = Wproj + 589824;
  ushort* Wff2  = Wff1 + 2359296;

  // weights -> bf16 (inputs restored every timed call, so convert every call)
  wcvt<<<1728, 256, 0, stream>>>(qkvw, Wqkv, 442368);
  wcvt<<<576,  256, 0, stream>>>(projw, Wproj, 147456);
  wcvt<<<2304, 256, 0, stream>>>(ff1w, Wff1, 589824);
  wcvt<<<2304, 256, 0, stream>>>(ff2w, Wff2, 589824);

  // LN1
  ln_k<<<3152, 256, 0, stream>>>(x, ln1w, ln1b, hb);

  // temporal conv on CLS tokens
  hipMemsetAsync(cq, 0, 2 * 49152 * sizeof(float), stream);
  conv_cls<<<dim3(12, 16), 256, 0, stream>>>(hb, cqw, ckw, cq, ck);

  // QKV projection (+cq/+ck fold, scatter); mt=99, 18 col-tiles
  gemm_k<0><<<1782, 256, 0, stream>>>(hb, Wqkv, 12608, 2304, 768, 99, qkvb,
      nullptr, nullptr, nullptr, cq, ck, cqb, ckb, Qb, Kb, Vb);

  // attention
  attn_k<<<768, 256, 0, stream>>>(Qb, Kb, Vb, Ob);

  // output projection + residual -> x1 (f32); 6 col-tiles
  gemm_k<1><<<594, 256, 0, stream>>>(Ob, Wproj, 12608, 768, 768, 99, projb,
      x1, nullptr, x, nullptr, nullptr, nullptr, nullptr, nullptr, nullptr, nullptr);

  // LN2
  ln_k<<<3152, 256, 0, stream>>>(x1, ln2w, ln2b, hb);

  // FF1 + GELU -> bf16; 24 col-tiles
  gemm_k<2><<<2376, 256, 0, stream>>>(hb, Wff1, 12608, 3072, 768, 99, ff1b,
      nullptr, ffh, nullptr, nullptr, nullptr, nullptr, nullptr, nullptr, nullptr, nullptr);

  // FF2 + residual -> out (f32); 6 col-tiles
  gemm_k<3><<<594, 256, 0, stream>>>(ffh, Wff2, 12608, 768, 3072, 99, ff2b,
      out, nullptr, x1, nullptr, nullptr, nullptr, nullptr, nullptr, nullptr, nullptr);
}